// Round 1
// 552.232 us; speedup vs baseline: 1.0289x; 1.0289x over previous
//
#include <hip/hip_runtime.h>
#include <math.h>

typedef __attribute__((ext_vector_type(8))) short s16x8;   // 8 bf16 (4 VGPRs)
typedef __attribute__((ext_vector_type(4))) float f32x4;   // MFMA accumulator
typedef __attribute__((ext_vector_type(4))) int   i32x4;

__device__ __forceinline__ short f2bf(float x){
  unsigned u = __float_as_uint(x);
  u += 0x7fff + ((u >> 16) & 1);        // round-to-nearest-even
  return (short)(u >> 16);
}
__device__ __forceinline__ float bf2f(short s){
  return __uint_as_float(((unsigned)(unsigned short)s) << 16);
}

// ---------------- fp32 -> bf16 convert (n % 4 == 0) ----------------
__global__ void k_cvt(const float* __restrict__ in, short* __restrict__ outb, int n4){
  int i = blockIdx.x*blockDim.x + threadIdx.x;
  if (i >= n4) return;
  float4 v = ((const float4*)in)[i];
  short4 u; u.x = f2bf(v.x); u.y = f2bf(v.y); u.z = f2bf(v.z); u.w = f2bf(v.w);
  ((short4*)outb)[i] = u;
}

// ---------------- weight transpose+convert: Wt[n][k] (bf16) from W[k][n] (fp32) ----------------
__global__ void k_wt(const float* W, short* Wt, int K){
  int idx = blockIdx.x*blockDim.x + threadIdx.x;
  if (idx >= 256*K) return;
  int n = idx / K, k = idx - n*K;
  Wt[idx] = f2bf(W[(size_t)k*256 + n]);
}

// c[h] = sum_f Wtp[h*F+f]*a_tp[h*F+f]
__global__ void k_cvec(const float* Wtp, const float* a_tp, float* c, int NH){
  __shared__ float buf[256];
  int t = threadIdx.x;
  buf[t] = Wtp[t] * a_tp[t];
  __syncthreads();
  int F = 256 / NH;
  if (t < NH){
    float s = 0.f;
    for (int f = 0; f < F; f++) s += buf[t*F + f];
    c[t] = s;
  }
}

// ---------------- CSR build (sort edges by target) ----------------
__global__ void k_zero(int* p, int n){
  int i = blockIdx.x*blockDim.x + threadIdx.x;
  if (i < n) p[i] = 0;
}
__global__ void k_hist(const int* tgt, int* counts, int E){
  int i = blockIdx.x*blockDim.x + threadIdx.x;
  if (i < E) atomicAdd(&counts[tgt[i]], 1);
}
__global__ void k_scan1(const int* counts, int* row_excl, int* partials, int N){
  __shared__ int buf[1024];
  int t = threadIdx.x; int i = blockIdx.x*1024 + t;
  int v = (i < N) ? counts[i] : 0;
  buf[t] = v; __syncthreads();
  for (int o = 1; o < 1024; o <<= 1){
    int x = (t >= o) ? buf[t-o] : 0;
    __syncthreads();
    buf[t] += x;
    __syncthreads();
  }
  if (i < N) row_excl[i] = buf[t] - v;
  if (t == 1023) partials[blockIdx.x] = buf[1023];
}
__global__ void k_scan2(int* partials, int NB){
  if (threadIdx.x == 0 && blockIdx.x == 0){
    int s = 0;
    for (int b = 0; b < NB; b++){ int v = partials[b]; partials[b] = s; s += v; }
  }
}
__global__ void k_scan3(int* row_start, const int* partials, int* cursor, int N, int E){
  int i = blockIdx.x*blockDim.x + threadIdx.x;
  if (i < N){
    int v = row_start[i] + partials[i >> 10];
    row_start[i] = v; cursor[i] = v;
  }
  if (i == 0) row_start[N] = E;
}
__global__ void k_scatter(const int* src, const int* tgt, const float* eprob,
                          int* cursor, int* src_s, float* tp_s, int E){
  int i = blockIdx.x*blockDim.x + threadIdx.x;
  if (i >= E) return;
  int tg = tgt[i];
  int p = atomicAdd(&cursor[tg], 1);
  src_s[p] = src[i]; tp_s[p] = eprob[i];
}

// ---------------- LDS-staged MFMA GEMM ----------------
// y=0: proj -> bf16 C1b + fused s_src/s_tgt (NH=16, from fp32 accs; skip if asrc null).
// y=1: skip -> bf16 C2b.
template<int KC>   // K/32 chunks: 4 (K=128) or 8 (K=256)
__global__ __launch_bounds__(256)
void k_gemm_lds(const short* __restrict__ Ab,
                const short* __restrict__ B1t, const short* __restrict__ B2t,
                short* __restrict__ C1b, short* __restrict__ C2b,
                const float* __restrict__ asrc, const float* __restrict__ atgt,
                float* __restrict__ s_src, float* __restrict__ s_tgt, int M){
  const int K = KC*32;
  __shared__ short lA[64*32];     // 4 KB
  __shared__ short lB[256*32];    // 16 KB
  const int tid  = threadIdx.x;
  const int lane = tid & 63;
  const int wave = tid >> 6;
  const int m16  = lane & 15;
  const int q    = lane >> 4;
  const int swz  = (m16 >> 1) & 3;
  const int r0   = blockIdx.x * 64;
  const bool first = (blockIdx.y == 0);
  const short* __restrict__ Bt = first ? B1t : B2t;
  short* __restrict__ Cb = first ? C1b : C2b;

  int arow = r0 + (tid >> 2); if (arow >= M) arow = M - 1;
  const int akq = (tid & 3) ^ ((tid >> 3) & 3);
  int bn[4], bkq[4];
  #pragma unroll
  for (int j = 0; j < 4; j++){
    int sj = j*256 + tid;
    bn[j]  = sj >> 2;
    bkq[j] = (sj & 3) ^ ((sj >> 3) & 3);
  }

  f32x4 acc[4][4];
  #pragma unroll
  for (int mi = 0; mi < 4; mi++)
    #pragma unroll
    for (int ni = 0; ni < 4; ni++) acc[mi][ni] = {0.f,0.f,0.f,0.f};

  s16x8 ra = *(const s16x8*)(Ab + (size_t)arow*K + akq*8);
  s16x8 rb[4];
  #pragma unroll
  for (int j = 0; j < 4; j++)
    rb[j] = *(const s16x8*)(Bt + (size_t)bn[j]*K + bkq[j]*8);

  for (int c = 0; c < KC; c++){
    __syncthreads();
    *(s16x8*)(lA + tid*8) = ra;
    #pragma unroll
    for (int j = 0; j < 4; j++)
      *(s16x8*)(lB + (j*256 + tid)*8) = rb[j];
    __syncthreads();

    if (c + 1 < KC){
      int k0 = (c+1)*32;
      ra = *(const s16x8*)(Ab + (size_t)arow*K + k0 + akq*8);
      #pragma unroll
      for (int j = 0; j < 4; j++)
        rb[j] = *(const s16x8*)(Bt + (size_t)bn[j]*K + k0 + bkq[j]*8);
    }

    s16x8 Af[4], Bf[4];
    #pragma unroll
    for (int mi = 0; mi < 4; mi++){
      int slot = (mi*16 + m16)*4 + (q ^ swz);
      Af[mi] = *(const s16x8*)(lA + slot*8);
    }
    #pragma unroll
    for (int ni = 0; ni < 4; ni++){
      int n = wave*64 + ni*16 + m16;
      int slot = n*4 + (q ^ swz);
      Bf[ni] = *(const s16x8*)(lB + slot*8);
    }
    #pragma unroll
    for (int mi = 0; mi < 4; mi++)
      #pragma unroll
      for (int ni = 0; ni < 4; ni++)
        acc[mi][ni] = __builtin_amdgcn_mfma_f32_16x16x32_bf16(Bf[ni], Af[mi], acc[mi][ni], 0, 0, 0);
  }

  #pragma unroll
  for (int mi = 0; mi < 4; mi++){
    int row = r0 + mi*16 + m16;
    bool ok = (row < M);
    #pragma unroll
    for (int ni = 0; ni < 4; ni++){
      if (ok){
        size_t o = (size_t)row*256 + wave*64 + ni*16 + q*4;
        short4 u; u.x = f2bf(acc[mi][ni][0]); u.y = f2bf(acc[mi][ni][1]);
        u.z = f2bf(acc[mi][ni][2]); u.w = f2bf(acc[mi][ni][3]);
        *(short4*)(Cb + o) = u;
      }
      if (first && asrc){
        // fused svec: head hh = wave*4+ni; lane holds features q*4..q*4+3 of row
        int hh = wave*4 + ni;
        const float* as = asrc + hh*16 + q*4;
        const float* at = atgt + hh*16 + q*4;
        float pss = acc[mi][ni][0]*as[0] + acc[mi][ni][1]*as[1]
                  + acc[mi][ni][2]*as[2] + acc[mi][ni][3]*as[3];
        float pst = acc[mi][ni][0]*at[0] + acc[mi][ni][1]*at[1]
                  + acc[mi][ni][2]*at[2] + acc[mi][ni][3]*at[3];
        pss += __shfl_xor(pss, 16); pss += __shfl_xor(pss, 32);
        pst += __shfl_xor(pst, 16); pst += __shfl_xor(pst, 32);
        if (ok && q == 0){
          s_src[row*16 + hh] = pss;
          s_tgt[row*16 + hh] = pst;
        }
      }
    }
  }
}

// ---------------- NH=1 score projections from bf16 proj (wave per node) ----------------
__global__ void k_svec1(const short* __restrict__ Pb,
                        const float* __restrict__ a_src, const float* __restrict__ a_tgt,
                        float* __restrict__ s_src, float* __restrict__ s_tgt, int N){
  int lane = threadIdx.x & 63;
  int node = blockIdx.x*(blockDim.x >> 6) + (threadIdx.x >> 6);
  if (node >= N) return;
  short4 p = ((const short4*)(Pb + (size_t)node*256))[lane];
  const float* as = a_src + lane*4;
  const float* at = a_tgt + lane*4;
  float f0 = bf2f(p.x), f1 = bf2f(p.y), f2 = bf2f(p.z), f3 = bf2f(p.w);
  float ss = f0*as[0] + f1*as[1] + f2*as[2] + f3*as[3];
  float st = f0*at[0] + f1*at[1] + f2*at[2] + f3*at[3];
  for (int o = 32; o > 0; o >>= 1){ ss += __shfl_xor(ss, o); st += __shfl_xor(st, o); }
  if (lane == 0){ s_src[node] = ss; s_tgt[node] = st; }
}

// ---------------- single-pass fused attention (bf16 proj gather, no max-subtraction) ----------------
// Two-phase per 16-edge segment, no cross-lane shuffles:
//  Phase A (scores): lane=(edge j4=lane&15, head-quad g=lane>>4). One float4 s_src
//    gather per lane covers 4 heads; 16 edges x 16 heads of w -> LDS wbuf[head][edge]
//    (row stride 20 words -> 2-way banks = free). Pad edges write w=0, sv clamped.
//  Phase B (aggregate): per 4-edge chunk: ds_read_b128 of w row (lane's head h2),
//    broadcast ds_read_b128 of sv, 4 coalesced proj-row gathers, fp32 FMAs.
//    Denominator d summed per-lane from the LDS w row -> no shuffle reduce at all.
template<int LN>
__global__ __launch_bounds__(256)
void k_attn16(const int* __restrict__ row_start, const int* __restrict__ src_s,
              const float* __restrict__ tp_s,
              const float* __restrict__ s_src, const float* __restrict__ s_tgt,
              const float* __restrict__ cvec,
              const short* __restrict__ projb, const short* __restrict__ skipb,
              const float* __restrict__ bias,
              const float* __restrict__ ln_g, const float* __restrict__ ln_b,
              short* __restrict__ houtb, int N){
  __shared__ __align__(16) float wbuf[4][16][20];   // [wave][head][edge(16)+pad]
  __shared__ __align__(16) int   svbuf[4][16];
  const int lane = threadIdx.x & 63;
  const int wave = threadIdx.x >> 6;
  const int node = blockIdx.x*4 + wave;
  if (node >= N) return;
  const int beg = row_start[node], end = row_start[node+1];

  const int h2 = lane >> 2;      // head owning this lane's 4 features (aggregation)
  const int j4 = lane & 15;      // edge slot (score phase)
  const int g  = lane >> 4;      // head-quad (score phase)

  const f32x4 stg = *(const f32x4*)(s_tgt + (size_t)node*16 + g*4);
  const f32x4 cg  = *(const f32x4*)(cvec + g*4);

  float d = 0.f;
  float acc0 = 0.f, acc1 = 0.f, acc2 = 0.f, acc3 = 0.f;

  for (int s0 = beg; s0 < end; s0 += 16){
    int cnt = end - s0; if (cnt > 16) cnt = 16;
    // ---- Phase A: scores for 16 edges x 16 heads ----
    int i  = s0 + j4;
    bool valid = (i < end);
    int ic = valid ? i : (end - 1);
    int sv = src_s[ic];
    float tp = tp_s[ic];
    f32x4 rv = *(const f32x4*)(s_src + (size_t)sv*16 + g*4);
    if (g == 0) svbuf[wave][j4] = sv;
    #pragma unroll
    for (int k = 0; k < 4; k++){
      float e = rv[k] + stg[k] + tp*cg[k];
      e = (e > 0.f) ? e : 0.2f*e;
      float w = valid ? __expf(e) : 0.f;
      wbuf[wave][g*4 + k][j4] = w;
    }
    // ---- Phase B: aggregate (pads carry w=0, sv clamped-valid) ----
    for (int j = 0; j < cnt; j += 4){
      f32x4 w4  = *(const f32x4*)&wbuf[wave][h2][j];
      i32x4 sv4 = *(const i32x4*)&svbuf[wave][j];
      short4 p0 = ((const short4*)(projb + (size_t)sv4.x*256))[lane];
      short4 p1 = ((const short4*)(projb + (size_t)sv4.y*256))[lane];
      short4 p2 = ((const short4*)(projb + (size_t)sv4.z*256))[lane];
      short4 p3 = ((const short4*)(projb + (size_t)sv4.w*256))[lane];
      d += (w4.x + w4.y) + (w4.z + w4.w);
      acc0 += w4.x*bf2f(p0.x) + w4.y*bf2f(p1.x) + w4.z*bf2f(p2.x) + w4.w*bf2f(p3.x);
      acc1 += w4.x*bf2f(p0.y) + w4.y*bf2f(p1.y) + w4.z*bf2f(p2.y) + w4.w*bf2f(p3.y);
      acc2 += w4.x*bf2f(p0.z) + w4.y*bf2f(p1.z) + w4.z*bf2f(p2.z) + w4.w*bf2f(p3.z);
      acc3 += w4.x*bf2f(p0.w) + w4.y*bf2f(p1.w) + w4.z*bf2f(p2.w) + w4.w*bf2f(p3.w);
    }
  }
  float inv = 1.f / (d + 1e-16f);

  short4 sk = ((const short4*)(skipb + (size_t)node*256))[lane];
  float acc[4];
  acc[0] = acc0*inv + bf2f(sk.x); acc[1] = acc1*inv + bf2f(sk.y);
  acc[2] = acc2*inv + bf2f(sk.z); acc[3] = acc3*inv + bf2f(sk.w);

  #pragma unroll
  for (int j = 0; j < 4; j++){
    float v = acc[j] + bias[lane*4 + j];
    acc[j] = (v > 0.f) ? v : (__expf(v) - 1.f);
  }
  if (LN){
    float s  = acc[0] + acc[1] + acc[2] + acc[3];
    float s2 = acc[0]*acc[0] + acc[1]*acc[1] + acc[2]*acc[2] + acc[3]*acc[3];
    for (int o = 32; o > 0; o >>= 1){ s += __shfl_xor(s, o); s2 += __shfl_xor(s2, o); }
    float mu  = s * (1.f/256.f);
    float var = s2 * (1.f/256.f) - mu*mu;
    float rs  = rsqrtf(var + 1e-5f);
    #pragma unroll
    for (int j = 0; j < 4; j++)
      acc[j] = (acc[j] - mu)*rs*ln_g[lane*4 + j] + ln_b[lane*4 + j];
  }
  short4 ub; ub.x = f2bf(acc[0]); ub.y = f2bf(acc[1]);
  ub.z = f2bf(acc[2]); ub.w = f2bf(acc[3]);
  ((short4*)(houtb + (size_t)node*256))[lane] = ub;
}

// NH=1 variant: Phase A scores 64 edges (one per lane) into LDS; Phase B aggregates
// per 4-edge chunk via broadcast ds_reads. No shuffles. bf16 identity skip, LN, bf16 out.
__global__ __launch_bounds__(256)
void k_attn1(const int* __restrict__ row_start, const int* __restrict__ src_s,
             const float* __restrict__ tp_s,
             const float* __restrict__ s_src, const float* __restrict__ s_tgt,
             const float* __restrict__ cvec,
             const short* __restrict__ projb, const short* __restrict__ skipb,
             const float* __restrict__ bias,
             const float* __restrict__ ln_g, const float* __restrict__ ln_b,
             short* __restrict__ houtb, int N){
  __shared__ __align__(16) float wb1[4][64];
  __shared__ __align__(16) int   sb1[4][64];
  const int lane = threadIdx.x & 63;
  const int wave = threadIdx.x >> 6;
  const int node = blockIdx.x*4 + wave;
  if (node >= N) return;
  const int beg = row_start[node], end = row_start[node+1];

  const float c0 = cvec[0];
  const float st = s_tgt[node];
  float d = 0.f;
  float acc0 = 0.f, acc1 = 0.f, acc2 = 0.f, acc3 = 0.f;

  for (int s0 = beg; s0 < end; s0 += 64){
    int cnt = end - s0; if (cnt > 64) cnt = 64;
    // ---- Phase A: one edge per lane ----
    int i  = s0 + lane;
    bool valid = (i < end);
    int ic = valid ? i : (end - 1);
    int sv = src_s[ic];
    float e = s_src[sv] + st + tp_s[ic]*c0;
    e = (e > 0.f) ? e : 0.2f*e;
    float w = valid ? __expf(e) : 0.f;
    wb1[wave][lane] = w;
    sb1[wave][lane] = sv;
    // ---- Phase B ----
    for (int j = 0; j < cnt; j += 4){
      f32x4 w4  = *(const f32x4*)&wb1[wave][j];
      i32x4 sv4 = *(const i32x4*)&sb1[wave][j];
      short4 p0 = ((const short4*)(projb + (size_t)sv4.x*256))[lane];
      short4 p1 = ((const short4*)(projb + (size_t)sv4.y*256))[lane];
      short4 p2 = ((const short4*)(projb + (size_t)sv4.z*256))[lane];
      short4 p3 = ((const short4*)(projb + (size_t)sv4.w*256))[lane];
      d += (w4.x + w4.y) + (w4.z + w4.w);
      acc0 += w4.x*bf2f(p0.x) + w4.y*bf2f(p1.x) + w4.z*bf2f(p2.x) + w4.w*bf2f(p3.x);
      acc1 += w4.x*bf2f(p0.y) + w4.y*bf2f(p1.y) + w4.z*bf2f(p2.y) + w4.w*bf2f(p3.y);
      acc2 += w4.x*bf2f(p0.z) + w4.y*bf2f(p1.z) + w4.z*bf2f(p2.z) + w4.w*bf2f(p3.z);
      acc3 += w4.x*bf2f(p0.w) + w4.y*bf2f(p1.w) + w4.z*bf2f(p2.w) + w4.w*bf2f(p3.w);
    }
  }
  float inv = 1.f / (d + 1e-16f);

  short4 sk = ((const short4*)(skipb + (size_t)node*256))[lane];
  float acc[4];
  acc[0] = acc0*inv + bf2f(sk.x); acc[1] = acc1*inv + bf2f(sk.y);
  acc[2] = acc2*inv + bf2f(sk.z); acc[3] = acc3*inv + bf2f(sk.w);

  #pragma unroll
  for (int j = 0; j < 4; j++){
    float v = acc[j] + bias[lane*4 + j];
    acc[j] = (v > 0.f) ? v : (__expf(v) - 1.f);
  }
  float s  = acc[0] + acc[1] + acc[2] + acc[3];
  float s2 = acc[0]*acc[0] + acc[1]*acc[1] + acc[2]*acc[2] + acc[3]*acc[3];
  for (int o = 32; o > 0; o >>= 1){ s += __shfl_xor(s, o); s2 += __shfl_xor(s2, o); }
  float mu  = s * (1.f/256.f);
  float var = s2 * (1.f/256.f) - mu*mu;
  float rs  = rsqrtf(var + 1e-5f);
  #pragma unroll
  for (int j = 0; j < 4; j++)
    acc[j] = (acc[j] - mu)*rs*ln_g[lane*4 + j] + ln_b[lane*4 + j];
  short4 ub; ub.x = f2bf(acc[0]); ub.y = f2bf(acc[1]);
  ub.z = f2bf(acc[2]); ub.w = f2bf(acc[3]);
  ((short4*)(houtb + (size_t)node*256))[lane] = ub;
}

// ---------------- final gather (bf16 h -> fp32 out) ----------------
__global__ void k_gather(const short* hb, const int* x, float* out, int R){
  int r = blockIdx.x, t = threadIdx.x;
  if (r >= R) return;
  out[(size_t)r*256 + t] = bf2f(hb[(size_t)x[r]*256 + t]);
}

extern "C" void kernel_launch(void* const* d_in, const int* in_sizes, int n_in,
                              void* d_out, int out_size, void* d_ws, size_t ws_size,
                              hipStream_t stream){
  const int N = in_sizes[0] / 128;   // 50000
  const int E = in_sizes[1] / 2;     // 800000
  const int R = in_sizes[3];         // 8192

  const float* nf    = (const float*)d_in[0];
  const int*   ei    = (const int*)d_in[1];
  const float* eprob = (const float*)d_in[2];
  const int*   xidx  = (const int*)d_in[3];
  const float* W0     = (const float*)d_in[4];
  const float* a_src0 = (const float*)d_in[5];
  const float* a_tgt0 = (const float*)d_in[6];
  const float* Wtp0   = (const float*)d_in[7];
  const float* a_tp0  = (const float*)d_in[8];
  const float* Wskip0 = (const float*)d_in[9];
  const float* b0     = (const float*)d_in[10];
  const float* W1     = (const float*)d_in[11];
  const float* a_src1 = (const float*)d_in[12];
  const float* a_tgt1 = (const float*)d_in[13];
  const float* Wtp1   = (const float*)d_in[14];
  const float* a_tp1  = (const float*)d_in[15];
  const float* Wskip1 = (const float*)d_in[16];
  const float* b1     = (const float*)d_in[17];
  const float* ln1_g  = (const float*)d_in[18];
  const float* ln1_b  = (const float*)d_in[19];
  const float* W2     = (const float*)d_in[20];
  const float* a_src2 = (const float*)d_in[21];
  const float* a_tgt2 = (const float*)d_in[22];
  const float* Wtp2   = (const float*)d_in[23];
  const float* a_tp2  = (const float*)d_in[24];
  const float* b2     = (const float*)d_in[25];
  const float* ln2_g  = (const float*)d_in[26];
  const float* ln2_b  = (const float*)d_in[27];

  // ---- workspace layout (~103 MB) ----
  char* ws = (char*)d_ws;
  size_t off = 0;
  auto alloc = [&](size_t bytes)->char*{
    char* p = ws + off; off = (off + bytes + 255) & ~(size_t)255; return p;
  };
  short* Pb        = (short*)alloc((size_t)N*256*2);   // proj, bf16 (per layer)
  short* hXb       = (short*)alloc((size_t)N*256*2);   // bf16 h: L0 out, then L1 out
  short* Skb       = (short*)alloc((size_t)N*256*2);   // skip GEMM out (L0/L1), then final h
  short* nfb       = (short*)alloc((size_t)N*128*2);   // bf16 node features
  float* s_src     = (float*)alloc((size_t)N*16*4);
  float* s_tgt     = (float*)alloc((size_t)N*16*4);
  float* cvec      = (float*)alloc(256);
  int*   counts    = (int*)alloc((size_t)N*4);
  int*   row_start = (int*)alloc((size_t)(N+1)*4);
  int*   partials  = (int*)alloc(256*4);
  int*   src_s     = (int*)alloc((size_t)E*4);
  float* tp_s      = (float*)alloc((size_t)E*4);
  short* W0t       = (short*)alloc((size_t)128*256*2);
  short* Ws0t      = (short*)alloc((size_t)128*256*2);
  short* W1t       = (short*)alloc((size_t)256*256*2);
  short* Ws1t      = (short*)alloc((size_t)256*256*2);
  short* W2t       = (short*)alloc((size_t)256*256*2);
  (void)ws_size; (void)n_in; (void)out_size;

  const int* src = ei;
  const int* tgt = ei + E;

  // ---- prep: weight transposes + nf convert + cvecs ----
  k_wt<<<(256*128+255)/256, 256, 0, stream>>>(W0,     W0t,  128);
  k_wt<<<(256*128+255)/256, 256, 0, stream>>>(Wskip0, Ws0t, 128);
  k_wt<<<(256*256+255)/256, 256, 0, stream>>>(W1,     W1t,  256);
  k_wt<<<(256*256+255)/256, 256, 0, stream>>>(Wskip1, Ws1t, 256);
  k_wt<<<(256*256+255)/256, 256, 0, stream>>>(W2,     W2t,  256);
  k_cvt<<<((N*128/4)+255)/256, 256, 0, stream>>>(nf, nfb, N*128/4);
  k_cvec<<<1, 256, 0, stream>>>(Wtp0, a_tp0, cvec + 0,  16);
  k_cvec<<<1, 256, 0, stream>>>(Wtp1, a_tp1, cvec + 16, 16);
  k_cvec<<<1, 256, 0, stream>>>(Wtp2, a_tp2, cvec + 32, 1);

  // ---- CSR build ----
  k_zero<<<(N+255)/256, 256, 0, stream>>>(counts, N);
  k_hist<<<(E+255)/256, 256, 0, stream>>>(tgt, counts, E);
  int NB = (N + 1023) / 1024;
  k_scan1<<<NB, 1024, 0, stream>>>(counts, row_start, partials, N);
  k_scan2<<<1, 64, 0, stream>>>(partials, NB);
  k_scan3<<<(N+255)/256, 256, 0, stream>>>(row_start, partials, counts, N, E);
  k_scatter<<<(E+255)/256, 256, 0, stream>>>(src, tgt, eprob, counts, src_s, tp_s, E);

  const int gt = (N + 63) / 64;   // GEMM m-tiles
  const int at = (N + 3) / 4;     // attn blocks (4 waves each)

  // ---- Layer 0: GAT(128 -> 16x16 concat), skip = nf @ Wskip0, ELU, no LN ----
  k_gemm_lds<4><<<dim3(gt,2), 256, 0, stream>>>(nfb, W0t, Ws0t, Pb, Skb,
                                                a_src0, a_tgt0, s_src, s_tgt, N);
  k_attn16<0><<<at, 256, 0, stream>>>(row_start, src_s, tp_s, s_src, s_tgt, cvec + 0,
                                      Pb, Skb, b0, nullptr, nullptr, hXb, N);

  // ---- Layer 1: GAT(256 -> 16x16 concat), skip = h @ Wskip1, ELU, LN ----
  k_gemm_lds<8><<<dim3(gt,2), 256, 0, stream>>>(hXb, W1t, Ws1t, Pb, Skb,
                                                a_src1, a_tgt1, s_src, s_tgt, N);
  k_attn16<1><<<at, 256, 0, stream>>>(row_start, src_s, tp_s, s_src, s_tgt, cvec + 16,
                                      Pb, Skb, b1, ln1_g, ln1_b, hXb, N);

  // ---- Layer 2: GAT(256 -> 1x256, avg = identity), identity skip, ELU, LN ----
  k_gemm_lds<8><<<dim3(gt,1), 256, 0, stream>>>(hXb, W2t, nullptr, Pb, nullptr,
                                                nullptr, nullptr, nullptr, nullptr, N);
  k_svec1<<<at, 256, 0, stream>>>(Pb, a_src2, a_tgt2, s_src, s_tgt, N);
  k_attn1<<<at, 256, 0, stream>>>(row_start, src_s, tp_s, s_src, s_tgt, cvec + 32,
                                  Pb, hXb, b2, ln2_g, ln2_b, Skb, N);

  // ---- gather rows into output (fp32) ----
  k_gather<<<R, 256, 0, stream>>>(Skb, xidx, (float*)d_out, R);
}